// Round 2
// baseline (533.665 us; speedup 1.0000x reference)
//
#include <hip/hip_runtime.h>
#include <hip/hip_bf16.h>

// out[b,o] = sum_g as[b,g]*ws[o,g]*dot(x4[b,g*128..],w4[o,..]) + bias[o]
// B=4096, O=11008, K=4096, GS=128, G=32.
// Harness normalized fp16 -> float32 (threshold = 2% of max|ref|, no bf16 floor).
// R2: prepass int4->int8 (exact) + scale transpose into d_ws, then i8 MFMA GEMM
//     with per-group i32 accumulate + f32 rescale. 128x128 tile, global_load_lds.

#define B_DIM 4096
#define O_DIM 11008
#define K_DIM 4096
#define G_NUM 32

#define NX4 2097152u        // 4096*2048/4 int4-groups for X
#define NW4 5636096u        // 11008*2048/4 for W
#define X8_BYTES  16777216u // 4096*4096
#define W8_BYTES  45088768u // 11008*4096

typedef int   i32x4 __attribute__((ext_vector_type(4)));
typedef float f32x4 __attribute__((ext_vector_type(4)));

// ---------------- prepass 1: unpack nibbles -> signed int8 ----------------
__device__ __forceinline__ unsigned pack2(int v) {
    // v in [0,256): low nibble = value k even, high nibble = k odd.
    // signed int4: val = (q^8)-8
    int t = v ^ 0x88;
    unsigned lo = (unsigned)(((t & 15) - 8) & 0xFF);
    unsigned hi = (unsigned)((((t >> 4) & 15) - 8) & 0xFF);
    return lo | (hi << 8);
}

__global__ __launch_bounds__(256)
void unpack_kernel(const int* __restrict__ xq, const int* __restrict__ wq,
                   unsigned char* __restrict__ X8, unsigned char* __restrict__ W8) {
    unsigned idx = blockIdx.x * 256u + threadIdx.x;   // one thread = 4 int32 -> 8 bytes
    const int* src;
    unsigned char* dst;
    if (idx < NX4) {
        src = xq + (size_t)idx * 4;
        dst = X8 + (size_t)idx * 8;
    } else {
        unsigned j = idx - NX4;
        src = wq + (size_t)j * 4;
        dst = W8 + (size_t)j * 8;
    }
    int4 v = *(const int4*)src;
    unsigned r0 = pack2(v.x) | (pack2(v.y) << 16);
    unsigned r1 = pack2(v.z) | (pack2(v.w) << 16);
    uint2 o; o.x = r0; o.y = r1;
    *(uint2*)dst = o;
}

// ---------------- prepass 2: transpose scales to [g][row] ----------------
__global__ __launch_bounds__(256)
void tscale_kernel(const float* __restrict__ as_, const float* __restrict__ ws_,
                   float* __restrict__ asT, float* __restrict__ wsT) {
    int bx = blockIdx.x, g = blockIdx.y, t = threadIdx.x;
    if (bx < 16) {
        int b = bx * 256 + t;                          // 16*256 = 4096
        asT[g * B_DIM + b] = as_[(size_t)b * G_NUM + g];
    } else {
        int o = (bx - 16) * 256 + t;                   // 43*256 = 11008
        wsT[(size_t)g * O_DIM + o] = ws_[(size_t)o * G_NUM + g];
    }
}

// ---------------- GEMM: i8 MFMA, per-group rescale ----------------
__global__ __launch_bounds__(256, 2)
void gemm_i8(const unsigned char* __restrict__ X8, const unsigned char* __restrict__ W8,
             const float* __restrict__ asT, const float* __restrict__ wsT,
             const float* __restrict__ bias, float* __restrict__ out) {
    __shared__ __align__(16) unsigned char A8[128 * 128];
    __shared__ __align__(16) unsigned char B8[128 * 128];

    const int tid  = threadIdx.x;
    const int wv   = tid >> 6;
    const int lane = tid & 63;
    const int quad = lane >> 4;
    const int lq   = lane & 15;
    const int bm   = blockIdx.x;   // batch tile (x-fastest -> co-resident share W? x shares bm)
    const int bn   = blockIdx.y;
    const int wm   = (wv & 1) << 6;
    const int wn   = (wv >> 1) << 6;

    f32x4 facc[4][4] = {};

    // staging: wave wv stages slabs wv*4..wv*4+3 (8 rows each) for both A and B.
    // LDS physical chunk p of row r holds logical 16B chunk c = p ^ (r&7)  (XOR swizzle).
    const int l8 = lane >> 3;                 // row within slab, == r&7
    const int c8 = lane & 7;                  // physical chunk
    const int sw_chunk = ((c8 ^ l8) << 4);    // swizzled byte offset in the 128B row slice
    const size_t xrow0 = (size_t)(bm * 128) * K_DIM;
    const size_t wrow0 = (size_t)(bn * 128) * K_DIM;

    for (int g = 0; g < G_NUM; ++g) {
        const int gb = g << 7;   // byte offset of group g within a 4096B row

#pragma unroll
        for (int s = 0; s < 4; ++s) {
            const int slab = (wv << 2) + s;
            const int row  = (slab << 3) + l8;
            const unsigned char* gpA = X8 + xrow0 + (size_t)row * K_DIM + gb + sw_chunk;
            const unsigned char* gpB = W8 + wrow0 + (size_t)row * K_DIM + gb + sw_chunk;
            __builtin_amdgcn_global_load_lds(
                (const __attribute__((address_space(1))) void*)gpA,
                (__attribute__((address_space(3))) void*)(A8 + (slab << 10)), 16, 0, 0);
            __builtin_amdgcn_global_load_lds(
                (const __attribute__((address_space(1))) void*)gpB,
                (__attribute__((address_space(3))) void*)(B8 + (slab << 10)), 16, 0, 0);
        }
        __syncthreads();

        i32x4 gacc[4][4] = {};
#pragma unroll
        for (int ks = 0; ks < 2; ++ks) {
            i32x4 av[4], bv[4];
            const int pa = ((((ks << 2) + quad) ^ (lq & 7)) << 4);  // swizzled chunk
#pragma unroll
            for (int i = 0; i < 4; ++i) {
                av[i] = *(const i32x4*)&A8[((wm + (i << 4) + lq) << 7) + pa];
                bv[i] = *(const i32x4*)&B8[((wn + (i << 4) + lq) << 7) + pa];
            }
#pragma unroll
            for (int i = 0; i < 4; ++i)
#pragma unroll
                for (int j = 0; j < 4; ++j)
                    gacc[i][j] = __builtin_amdgcn_mfma_i32_16x16x64_i8(av[i], bv[j], gacc[i][j], 0, 0, 0);
        }

        // per-group rescale: facc += as[m]*ws[n]*gacc  (C/D: col=lq, row=quad*4+r)
        f32x4 asr[4];
        float wsn[4];
#pragma unroll
        for (int i = 0; i < 4; ++i)
            asr[i] = *(const f32x4*)&asT[(g << 12) + bm * 128 + wm + (i << 4) + (quad << 2)];
#pragma unroll
        for (int j = 0; j < 4; ++j)
            wsn[j] = wsT[(size_t)g * O_DIM + bn * 128 + wn + (j << 4) + lq];
#pragma unroll
        for (int i = 0; i < 4; ++i)
#pragma unroll
            for (int j = 0; j < 4; ++j)
#pragma unroll
                for (int r = 0; r < 4; ++r)
                    facc[i][j][r] += (asr[i][r] * wsn[j]) * (float)gacc[i][j][r];

        __syncthreads();
    }

    // epilogue: out is float32
    const int n0 = bn * 128 + wn + lq;
    const int m0 = bm * 128 + wm + (quad << 2);
    float bvs[4];
#pragma unroll
    for (int j = 0; j < 4; ++j) bvs[j] = bias[n0 + (j << 4)];
#pragma unroll
    for (int i = 0; i < 4; ++i) {
#pragma unroll
        for (int r = 0; r < 4; ++r) {
            float* orow = out + (size_t)(m0 + (i << 4) + r) * O_DIM;
#pragma unroll
            for (int j = 0; j < 4; ++j)
                orow[n0 + (j << 4)] = facc[i][j][r] + bvs[j];
        }
    }
}

extern "C" void kernel_launch(void* const* d_in, const int* in_sizes, int n_in,
                              void* d_out, int out_size, void* d_ws, size_t ws_size,
                              hipStream_t stream) {
    const int*   xq   = (const int*)d_in[0];
    const float* as_  = (const float*)d_in[1];
    const int*   wq   = (const int*)d_in[2];
    const float* ws_  = (const float*)d_in[3];
    const float* bias = (const float*)d_in[4];
    float* out        = (float*)d_out;

    unsigned char* X8 = (unsigned char*)d_ws;
    unsigned char* W8 = X8 + X8_BYTES;
    float* asT = (float*)((unsigned char*)d_ws + X8_BYTES + W8_BYTES);  // 61,865,984
    float* wsT = asT + (size_t)G_NUM * B_DIM;                           // +524,288 B
    // total ws use: 63,799,296 B (~61 MB)

    unpack_kernel<<<(NX4 + NW4) / 256, 256, 0, stream>>>(xq, wq, X8, W8);
    tscale_kernel<<<dim3(59, 32), 256, 0, stream>>>(as_, ws_, asT, wsT);
    gemm_i8<<<dim3(B_DIM / 128, O_DIM / 128), 256, 0, stream>>>(X8, W8, asT, wsT, bias, out);
}